// Round 4
// baseline (236.175 us; speedup 1.0000x reference)
//
#include <hip/hip_runtime.h>
#include <hip/hip_cooperative_groups.h>
#include <stdint.h>
#include <math.h>

#define NROWS 8192
#define DDIM  256
#define BM    128
#define BN    128
#define GJ    8                         // column groups (grid.y)
#define COLS_PER_GROUP (NROWS / GJ)     // 1024

constexpr float INV_T  = 1.0f / 0.07f;  // fixed LSE max M0 = 1/T (|logit| <= 1/T)
constexpr float LOG2E  = 1.44269504f;
constexpr float K1     = INV_T * LOG2E; // exp2 arg: fma(acc, K1, -K1)

typedef __bf16 bf16x8 __attribute__((ext_vector_type(8)));
typedef float  f32x4  __attribute__((ext_vector_type(4)));

namespace cg = cooperative_groups;

__device__ __forceinline__ void async_copy16(const uint16_t* g, uint16_t* l) {
    __builtin_amdgcn_global_load_lds(
        (const __attribute__((address_space(1))) uint32_t*)g,
        (__attribute__((address_space(3))) uint32_t*)l, 16, 0, 0);
}

__device__ inline uint16_t f2bf(float f) {
    uint32_t u = __float_as_uint(f);
    u += 0x7fffu + ((u >> 16) & 1u);    // RNE
    return (uint16_t)(u >> 16);
}

// ---- Phase 1 body: normalize one row (64 lanes, float4/lane), emit bf16.
__device__ __forceinline__ void norm_row(const float* src, uint16_t* dstb, int lane) {
    float4 v = ((const float4*)src)[lane];
    float ss = v.x*v.x + v.y*v.y + v.z*v.z + v.w*v.w;
    #pragma unroll
    for (int m = 1; m < 64; m <<= 1) ss += __shfl_xor(ss, m, 64);
    float r = rsqrtf(ss);
    ushort4 o;
    o.x = f2bf(v.x * r); o.y = f2bf(v.y * r); o.z = f2bf(v.z * r); o.w = f2bf(v.w * r);
    ((ushort4*)dstb)[lane] = o;
}

// ---- Phase 2 body: round-0 fused GEMM + fixed-max sum-of-exp (proven 53.6us)
// with ONE change: corrected B swizzle. Buffer rows are 64B (4 x 16B groups);
// storing chunk p of row r at p^((r>>1)&3) makes a 16-lane b128 read phase
// cover bank-group 4*(r&1) + p = all 8 groups exactly twice -> conflict-free.
// (Round-0's quad^(rk&3) left lanes {x,x+4,x+8,x+12} on one group: 4-way.)
__device__ __forceinline__ void gemm_phase(
    const uint16_t* __restrict__ qb, const uint16_t* __restrict__ kb,
    float* __restrict__ lpT, float* __restrict__ gpl,
    uint16_t* lds_q, uint16_t* lds_k, int bx, int by)
{
    const int tid    = threadIdx.x;
    const int wave   = tid >> 6;
    const int lane   = tid & 63;
    const int quad   = lane >> 4;
    const int lanelo = lane & 15;
    const int wr     = wave >> 1;
    const int wc     = wave & 1;
    const int rowBase      = bx * BM;
    const int colGroupBase = by * COLS_PER_GROUP;

    // ---- Stage Q tile once: 4096 chunks of 16B, source-swizzled (proven clean).
    #pragma unroll
    for (int i = 0; i < 16; ++i) {
        int S   = (wave * 16 + i) * 64 + lane;          // lds chunk id
        int row = S >> 5;
        int ch  = (S & 31) ^ (row & 31);                // swizzle: source chunk
        async_copy16(qb + (size_t)(rowBase + row) * DDIM + ch * 8,
                     lds_q + (size_t)(wave * 16 + i) * 512);
    }

    // ---- K staging lane constants (chunk = 16B; 4 chunks per 32-col row).
    int kS0   = wave * 128 + lane;                      // i=0 chunk id in 512-chunk buffer
    int krow0 = kS0 >> 2;
    int kch0  = (lane & 3) ^ ((krow0 >> 1) & 3);        // FIXED source swizzle
    int krow1 = (kS0 + 64) >> 2;
    int kch1  = (lane & 3) ^ ((krow1 >> 1) & 3);        // FIXED
    const uint16_t* kbase0 = kb + (size_t)(colGroupBase + krow0) * DDIM + kch0 * 8;
    const uint16_t* kbase1 = kb + (size_t)(colGroupBase + krow1) * DDIM + kch1 * 8;
    uint16_t* kl0 = lds_k + wave * 1024;                // wave-uniform dest (i=0)

    // phase 0 (jt=0, kk=0) into buf 0
    async_copy16(kbase0, kl0);
    async_copy16(kbase1, kl0 + 512);
    __syncthreads();    // Q + first K chunk visible

    // ---- Fragment address constants.
    int rq[4], rq31[4];
    #pragma unroll
    for (int mt = 0; mt < 4; ++mt) {
        rq[mt]   = wr * 64 + mt * 16 + lanelo;
        rq31[mt] = rq[mt] & 31;
    }
    int bvoff[4];
    #pragma unroll
    for (int nt = 0; nt < 4; ++nt) {
        int rk = wc * 64 + nt * 16 + lanelo;
        bvoff[nt] = rk * 32 + (quad ^ ((lanelo >> 1) & 3)) * 8;  // FIXED read swizzle
    }

    float l_run[16];
    #pragma unroll
    for (int i = 0; i < 16; ++i) l_run[i] = 0.f;

    for (int jt = 0; jt < 8; ++jt) {
        const int colT = colGroupBase + jt * BN;

        f32x4 acc[4][4];
        #pragma unroll
        for (int mt = 0; mt < 4; ++mt)
            #pragma unroll
            for (int nt = 0; nt < 4; ++nt)
                acc[mt][nt] = (f32x4){0.f, 0.f, 0.f, 0.f};

        #pragma unroll
        for (int kk = 0; kk < 8; ++kk) {
            const int p    = (jt << 3) + kk;
            const int buf  = p & 1;
            const int nbuf = buf ^ 1;

            // Issue next chunk's loads (drained only at the NEXT barrier).
            if (p < 63) {
                int np  = p + 1;
                int off = ((np >> 3) << 15) + ((np & 7) << 5);  // njt*128*256 + nkk*32
                uint16_t* ld = lds_k + nbuf * 4096 + wave * 1024;
                async_copy16(kbase0 + off, ld);
                async_copy16(kbase1 + off, ld + 512);
            }

            // Compute on buf.
            bf16x8 av[4], bv[4];
            #pragma unroll
            for (int mt = 0; mt < 4; ++mt) {
                int chp = ((kk << 2) + quad) ^ rq31[mt];
                av[mt] = *(const bf16x8*)&lds_q[rq[mt] * 256 + chp * 8];
            }
            #pragma unroll
            for (int nt = 0; nt < 4; ++nt)
                bv[nt] = *(const bf16x8*)&lds_k[buf * 4096 + bvoff[nt]];
            #pragma unroll
            for (int mt = 0; mt < 4; ++mt)
                #pragma unroll
                for (int nt = 0; nt < 4; ++nt)
                    acc[mt][nt] = __builtin_amdgcn_mfma_f32_16x16x32_bf16(av[mt], bv[nt], acc[mt][nt], 0, 0, 0);

            __syncthreads();    // publish chunk p+1's writes / guard buf reuse
        }

        // Epilogue: fixed-max exp accumulate (registers only).
        int gcol[4];
        #pragma unroll
        for (int nt = 0; nt < 4; ++nt) gcol[nt] = colT + wc * 64 + nt * 16 + lanelo;
        #pragma unroll
        for (int mt = 0; mt < 4; ++mt) {
            #pragma unroll
            for (int rg = 0; rg < 4; ++rg) {
                int grow = rowBase + wr * 64 + mt * 16 + quad * 4 + rg;
                float s = 0.f;
                #pragma unroll
                for (int nt = 0; nt < 4; ++nt) {
                    float a = acc[mt][nt][rg];
                    float e = exp2f(fmaf(a, K1, -K1));
                    if (grow == gcol[nt]) { lpT[grow] = a * INV_T; e = 0.f; }  // diag term ~e^-157
                    s += e;
                }
                l_run[mt * 4 + rg] += s;
            }
        }
    }

    // Cross-lane reduce over the 16 lanelo lanes (same row, different cols).
    #pragma unroll
    for (int i = 0; i < 16; ++i) {
        float v = l_run[i];
        v += __shfl_xor(v, 1, 64);
        v += __shfl_xor(v, 2, 64);
        v += __shfl_xor(v, 4, 64);
        v += __shfl_xor(v, 8, 64);
        l_run[i] = v;
    }
    // All LDS reads/writes done (last barrier passed; no loads in flight).
    float* pl = (float*)lds_k;      // 256 floats scratch
    if (lanelo == 0) {
        #pragma unroll
        for (int mt = 0; mt < 4; ++mt)
            #pragma unroll
            for (int rg = 0; rg < 4; ++rg) {
                int lr = wr * 64 + mt * 16 + quad * 4 + rg;
                pl[wc * 128 + lr] = l_run[mt * 4 + rg];
            }
    }
    __syncthreads();
    if (tid < 128) {
        float L = pl[tid] + pl[128 + tid];
        gpl[(size_t)by * NROWS + rowBase + tid] = L;
    }
}

// ---- Fused cooperative kernel: norm -> grid.sync -> GEMM -> grid.sync -> finalize.
// Grid 64x8 = 512 blocks x 256 thr, 80KB LDS, bounds(256,2): exactly 2 blocks/CU
// x 256 CU co-resident, so cooperative launch validates.
__global__ __launch_bounds__(256, 2) void fused_kernel(
    const float* __restrict__ fq, const float* __restrict__ fk,
    uint16_t* __restrict__ qb, uint16_t* __restrict__ kb,
    float* __restrict__ lpT, float* __restrict__ gpl,
    float* __restrict__ out)
{
    __shared__ __align__(16) uint16_t lds_q[BM * DDIM];     // 65536 B
    __shared__ __align__(16) uint16_t lds_k[2 * BN * 32];   // 16384 B

    const int wave = threadIdx.x >> 6;
    const int lane = threadIdx.x & 63;
    const int flat = blockIdx.y * gridDim.x + blockIdx.x;   // 0..511

    // Phase 1: this block normalizes 32 of the 16384 rows (q-space then k-space).
    #pragma unroll
    for (int i = 0; i < 8; ++i) {
        int row = flat * 32 + wave * 8 + i;
        if (row < NROWS) norm_row(fq + (size_t)row * DDIM, qb + (size_t)row * DDIM, lane);
        else {
            int r = row - NROWS;
            norm_row(fk + (size_t)r * DDIM, kb + (size_t)r * DDIM, lane);
        }
    }

    cg::this_grid().sync();

    gemm_phase(qb, kb, lpT, gpl, lds_q, lds_k, blockIdx.x, blockIdx.y);

    cg::this_grid().sync();

    // Phase 3: this block finalizes 16 rows. loss = M0 + log(L) - l_pos/T.
    int t = flat * 16 + threadIdx.x;
    if (threadIdx.x < 16) {
        float L = 0.f;
        #pragma unroll
        for (int g = 0; g < GJ; ++g) L += gpl[g * NROWS + t];
        float lp = lpT[t];
        L += __expf(lp - INV_T);
        out[t] = INV_T + __logf(L) - lp;
    }
}

// ---- Fallback path (if cooperative launch is rejected): 3 separate kernels.
__global__ __launch_bounds__(256) void norm_convert_kernel(
    const float* __restrict__ fq, const float* __restrict__ fk,
    uint16_t* __restrict__ qb, uint16_t* __restrict__ kb)
{
    const int wave = threadIdx.x >> 6;
    const int lane = threadIdx.x & 63;
    const int row  = blockIdx.x * 4 + wave;
    if (row < NROWS) norm_row(fq + (size_t)row * DDIM, qb + (size_t)row * DDIM, lane);
    else {
        int r = row - NROWS;
        norm_row(fk + (size_t)r * DDIM, kb + (size_t)r * DDIM, lane);
    }
}

__global__ __launch_bounds__(256, 2) void nce_main_kernel(
    const uint16_t* __restrict__ qb, const uint16_t* __restrict__ kb,
    float* __restrict__ lpT, float* __restrict__ gpl)
{
    __shared__ __align__(16) uint16_t lds_q[BM * DDIM];
    __shared__ __align__(16) uint16_t lds_k[2 * BN * 32];
    gemm_phase(qb, kb, lpT, gpl, lds_q, lds_k, blockIdx.x, blockIdx.y);
}

__global__ __launch_bounds__(256) void finalize_kernel(
    const float* __restrict__ gpl, const float* __restrict__ lpT,
    float* __restrict__ out)
{
    int t = blockIdx.x * 256 + threadIdx.x;
    if (t >= NROWS) return;
    float L = 0.f;
    #pragma unroll
    for (int g = 0; g < GJ; ++g) L += gpl[g * NROWS + t];
    float lp = lpT[t];
    L += __expf(lp - INV_T);
    out[t] = INV_T + __logf(L) - lp;
}

extern "C" void kernel_launch(void* const* d_in, const int* in_sizes, int n_in,
                              void* d_out, int out_size, void* d_ws, size_t ws_size,
                              hipStream_t stream) {
    const float* fq = (const float*)d_in[0];
    const float* fk = (const float*)d_in[1];
    char* ws = (char*)d_ws;
    // layout: qb 4MB | kb 4MB | lpT 32KB | gpl 256KB
    uint16_t* qb  = (uint16_t*)(ws);
    uint16_t* kb  = (uint16_t*)(ws + 4194304);
    float*    lpT = (float*)(ws + 8388608);
    float*    gpl = (float*)(ws + 8421376);
    float*    outp = (float*)d_out;

    void* kargs[] = { (void*)&fq, (void*)&fk, (void*)&qb, (void*)&kb,
                      (void*)&lpT, (void*)&gpl, (void*)&outp };
    hipError_t e = hipLaunchCooperativeKernel(
        (const void*)fused_kernel, dim3(NROWS / BM, GJ), dim3(256), kargs, 0, stream);
    if (e != hipSuccess) {
        (void)hipGetLastError();    // clear sticky error, use 3-launch fallback
        norm_convert_kernel<<<(2 * NROWS) / 4, 256, 0, stream>>>(fq, fk, qb, kb);
        dim3 grid(NROWS / BM, GJ);
        nce_main_kernel<<<grid, 256, 0, stream>>>(qb, kb, lpT, gpl);
        finalize_kernel<<<NROWS / 256, 256, 0, stream>>>(gpl, lpT, outp);
    }
}

// Round 5
// 111.546 us; speedup vs baseline: 2.1173x; 2.1173x over previous
//
#include <hip/hip_runtime.h>
#include <stdint.h>
#include <math.h>

#define NROWS 8192
#define DDIM  256
#define BM    128
#define BN    128
#define GJ    8                         // column groups (grid.y)
#define COLS_PER_GROUP (NROWS / GJ)     // 1024

constexpr float INV_T  = 1.0f / 0.07f;  // fixed LSE max M0 = 1/T (|logit| <= 1/T)
constexpr float LOG2E  = 1.44269504f;
constexpr float K1     = INV_T * LOG2E; // exp2 arg: fma(acc, K1, -K1)

typedef __bf16 bf16x8 __attribute__((ext_vector_type(8)));
typedef float  f32x4  __attribute__((ext_vector_type(4)));

__device__ __forceinline__ void async_copy16(const uint16_t* g, uint16_t* l) {
    __builtin_amdgcn_global_load_lds(
        (const __attribute__((address_space(1))) uint32_t*)g,
        (__attribute__((address_space(3))) uint32_t*)l, 16, 0, 0);
}

__device__ inline uint16_t f2bf(float f) {
    uint32_t u = __float_as_uint(f);
    u += 0x7fffu + ((u >> 16) & 1u);    // RNE
    return (uint16_t)(u >> 16);
}

// Kernel 1: normalize each row to unit length, emit bf16. One wave per row.
__global__ __launch_bounds__(256) void norm_convert_kernel(
    const float* __restrict__ fq, const float* __restrict__ fk,
    uint16_t* __restrict__ qb, uint16_t* __restrict__ kb)
{
    const int wave = threadIdx.x >> 6;
    const int lane = threadIdx.x & 63;
    const int row  = blockIdx.x * 4 + wave;

    const float* src; uint16_t* dstb;
    if (row < NROWS) {
        src = fq + (size_t)row * DDIM; dstb = qb + (size_t)row * DDIM;
    } else {
        int r = row - NROWS;
        src = fk + (size_t)r * DDIM; dstb = kb + (size_t)r * DDIM;
    }

    float4 v = ((const float4*)src)[lane];
    float ss = v.x*v.x + v.y*v.y + v.z*v.z + v.w*v.w;
    #pragma unroll
    for (int m = 1; m < 64; m <<= 1) ss += __shfl_xor(ss, m, 64);
    float r = rsqrtf(ss);

    ushort4 o;
    o.x = f2bf(v.x * r); o.y = f2bf(v.y * r); o.z = f2bf(v.z * r); o.w = f2bf(v.w * r);
    ((ushort4*)dstb)[lane] = o;
}

// Kernel 2: round-0 structure (proven 53.6us) + corrected K swizzle (proven
// conflict-free in round 4: SQ_LDS_BANK_CONFLICT 2.1M -> 0).
// K buffer rows are 64B = 4 x 16B bank-groups; storing chunk p of row r at
// p^((r>>1)&3) makes each 16-lane b128 read phase cover bank-group
// 4*(r&1)+p = all 8 groups exactly twice -> conflict-free. (Round-0's
// quad^(rk&3) left lanes {x,x+4,x+8,x+12} on one group: structural 4-way.)
// Q tile (128x256) in LDS (staged once, async, 32-chunk row swizzle); K in
// BK=32 double-buffered chunks (1-chunk prefetch). 4 waves in 2x2, each 64x64
// via 16x16x32 bf16 MFMA; fixed-max (M0=1/T) sum-of-exp epilogue per tile.
__global__ __launch_bounds__(256, 2) void nce_main_kernel(
    const uint16_t* __restrict__ qb, const uint16_t* __restrict__ kb,
    float* __restrict__ lpT, float* __restrict__ gpl)
{
    __shared__ __align__(16) uint16_t lds_q[BM * DDIM];     // 65536 B, swizzled
    __shared__ __align__(16) uint16_t lds_k[2 * BN * 32];   // 16384 B, 2 bufs, swizzled

    const int tid    = threadIdx.x;
    const int wave   = tid >> 6;
    const int lane   = tid & 63;
    const int quad   = lane >> 4;
    const int lanelo = lane & 15;
    const int wr     = wave >> 1;
    const int wc     = wave & 1;
    const int rowBase      = blockIdx.x * BM;
    const int colGroupBase = blockIdx.y * COLS_PER_GROUP;

    // ---- Stage Q tile once: 4096 chunks of 16B, 16 instrs/wave, source-swizzled.
    #pragma unroll
    for (int i = 0; i < 16; ++i) {
        int S   = (wave * 16 + i) * 64 + lane;          // lds chunk id
        int row = S >> 5;
        int ch  = (S & 31) ^ (row & 31);                // swizzle: source chunk
        async_copy16(qb + (size_t)(rowBase + row) * DDIM + ch * 8,
                     lds_q + (size_t)(wave * 16 + i) * 512);
    }

    // ---- K staging lane constants (chunk = 16B; 4 chunks per 32-col row).
    int kS0   = wave * 128 + lane;                      // i=0 chunk id in 512-chunk buffer
    int krow0 = kS0 >> 2;
    int kch0  = (lane & 3) ^ ((krow0 >> 1) & 3);        // FIXED source swizzle
    int krow1 = (kS0 + 64) >> 2;
    int kch1  = (lane & 3) ^ ((krow1 >> 1) & 3);        // FIXED
    const uint16_t* kbase0 = kb + (size_t)(colGroupBase + krow0) * DDIM + kch0 * 8;
    const uint16_t* kbase1 = kb + (size_t)(colGroupBase + krow1) * DDIM + kch1 * 8;
    uint16_t* kl0 = lds_k + wave * 1024;                // wave-uniform dest (i=0)

    // phase 0 (jt=0, kk=0) into buf 0
    async_copy16(kbase0, kl0);
    async_copy16(kbase1, kl0 + 512);
    __syncthreads();    // Q + first K chunk visible

    // ---- Fragment address constants.
    int rq[4], rq31[4];
    #pragma unroll
    for (int mt = 0; mt < 4; ++mt) {
        rq[mt]   = wr * 64 + mt * 16 + lanelo;
        rq31[mt] = rq[mt] & 31;
    }
    int bvoff[4];
    #pragma unroll
    for (int nt = 0; nt < 4; ++nt) {
        int rk = wc * 64 + nt * 16 + lanelo;
        bvoff[nt] = rk * 32 + (quad ^ ((lanelo >> 1) & 3)) * 8;  // FIXED read swizzle
    }

    float l_run[16];
    #pragma unroll
    for (int i = 0; i < 16; ++i) l_run[i] = 0.f;

    for (int jt = 0; jt < 8; ++jt) {
        const int colT = colGroupBase + jt * BN;

        f32x4 acc[4][4];
        #pragma unroll
        for (int mt = 0; mt < 4; ++mt)
            #pragma unroll
            for (int nt = 0; nt < 4; ++nt)
                acc[mt][nt] = (f32x4){0.f, 0.f, 0.f, 0.f};

        #pragma unroll
        for (int kk = 0; kk < 8; ++kk) {
            const int p    = (jt << 3) + kk;
            const int buf  = p & 1;
            const int nbuf = buf ^ 1;

            // Issue next chunk's loads (drained only at the NEXT barrier).
            if (p < 63) {
                int np  = p + 1;
                int off = ((np >> 3) << 15) + ((np & 7) << 5);  // njt*128*256 + nkk*32
                uint16_t* ld = lds_k + nbuf * 4096 + wave * 1024;
                async_copy16(kbase0 + off, ld);
                async_copy16(kbase1 + off, ld + 512);
            }

            // Compute on buf.
            bf16x8 av[4], bv[4];
            #pragma unroll
            for (int mt = 0; mt < 4; ++mt) {
                int chp = ((kk << 2) + quad) ^ rq31[mt];
                av[mt] = *(const bf16x8*)&lds_q[rq[mt] * 256 + chp * 8];
            }
            #pragma unroll
            for (int nt = 0; nt < 4; ++nt)
                bv[nt] = *(const bf16x8*)&lds_k[buf * 4096 + bvoff[nt]];
            #pragma unroll
            for (int mt = 0; mt < 4; ++mt)
                #pragma unroll
                for (int nt = 0; nt < 4; ++nt)
                    acc[mt][nt] = __builtin_amdgcn_mfma_f32_16x16x32_bf16(av[mt], bv[nt], acc[mt][nt], 0, 0, 0);

            __syncthreads();    // publish chunk p+1's writes / guard buf reuse
        }

        // Epilogue: fixed-max exp accumulate (registers only).
        int gcol[4];
        #pragma unroll
        for (int nt = 0; nt < 4; ++nt) gcol[nt] = colT + wc * 64 + nt * 16 + lanelo;
        #pragma unroll
        for (int mt = 0; mt < 4; ++mt) {
            #pragma unroll
            for (int rg = 0; rg < 4; ++rg) {
                int grow = rowBase + wr * 64 + mt * 16 + quad * 4 + rg;
                float s = 0.f;
                #pragma unroll
                for (int nt = 0; nt < 4; ++nt) {
                    float a = acc[mt][nt][rg];
                    float e = exp2f(fmaf(a, K1, -K1));
                    if (grow == gcol[nt]) { lpT[grow] = a * INV_T; e = 0.f; }  // diag term ~e^-157
                    s += e;
                }
                l_run[mt * 4 + rg] += s;
            }
        }
    }

    // Cross-lane reduce over the 16 lanelo lanes (same row, different cols).
    #pragma unroll
    for (int i = 0; i < 16; ++i) {
        float v = l_run[i];
        v += __shfl_xor(v, 1, 64);
        v += __shfl_xor(v, 2, 64);
        v += __shfl_xor(v, 4, 64);
        v += __shfl_xor(v, 8, 64);
        l_run[i] = v;
    }
    // All LDS reads/writes done (last barrier passed; no loads in flight).
    float* pl = (float*)lds_k;      // 256 floats scratch
    if (lanelo == 0) {
        #pragma unroll
        for (int mt = 0; mt < 4; ++mt)
            #pragma unroll
            for (int rg = 0; rg < 4; ++rg) {
                int lr = wr * 64 + mt * 16 + quad * 4 + rg;
                pl[wc * 128 + lr] = l_run[mt * 4 + rg];
            }
    }
    __syncthreads();
    if (tid < 128) {
        float L = pl[tid] + pl[128 + tid];
        gpl[(size_t)blockIdx.y * NROWS + rowBase + tid] = L;
    }
}

// Kernel 3: merge GJ partial sums + l_pos; loss = M0 + log(L) - l_pos/T.
__global__ __launch_bounds__(256) void finalize_kernel(
    const float* __restrict__ gpl, const float* __restrict__ lpT,
    float* __restrict__ out)
{
    int t = blockIdx.x * 256 + threadIdx.x;
    if (t >= NROWS) return;
    float L = 0.f;
    #pragma unroll
    for (int g = 0; g < GJ; ++g) L += gpl[g * NROWS + t];
    float lp = lpT[t];
    L += __expf(lp - INV_T);
    out[t] = INV_T + __logf(L) - lp;
}

extern "C" void kernel_launch(void* const* d_in, const int* in_sizes, int n_in,
                              void* d_out, int out_size, void* d_ws, size_t ws_size,
                              hipStream_t stream) {
    const float* fq = (const float*)d_in[0];
    const float* fk = (const float*)d_in[1];
    char* ws = (char*)d_ws;
    // layout: qb 4MB | kb 4MB | lpT 32KB | gpl 256KB
    uint16_t* qb  = (uint16_t*)(ws);
    uint16_t* kb  = (uint16_t*)(ws + 4194304);
    float*    lpT = (float*)(ws + 8388608);
    float*    gpl = (float*)(ws + 8421376);

    norm_convert_kernel<<<(2 * NROWS) / 4, 256, 0, stream>>>(fq, fk, qb, kb);
    dim3 grid(NROWS / BM, GJ);
    nce_main_kernel<<<grid, 256, 0, stream>>>(qb, kb, lpT, gpl);
    finalize_kernel<<<NROWS / 256, 256, 0, stream>>>(gpl, lpT, (float*)d_out);
}